// Round 2
// baseline (122.202 us; speedup 1.0000x reference)
//
#include <hip/hip_runtime.h>
#include <hip/hip_bf16.h>

#define NUM_SAMPLES 256
#define CH 64
#define IMG_H 512
#define IMG_W 512
#define BATCH 8
#define NBLOCKS (BATCH * NUM_SAMPLES)   // 2048

__device__ __forceinline__ float wave_reduce_sum(float v) {
    // full-wave (64-lane) butterfly; all lanes end with the total
    v += __shfl_xor(v, 32, 64);
    v += __shfl_xor(v, 16, 64);
    v += __shfl_xor(v, 8, 64);
    v += __shfl_xor(v, 4, 64);
    v += __shfl_xor(v, 2, 64);
    v += __shfl_xor(v, 1, 64);
    return v;
}

// One wave per (b, s): lane = channel. Last-arriving block does the final sum.
__global__ void __launch_bounds__(64)
fused_sample_diff_kernel(const float* __restrict__ fq,
                         const float* __restrict__ fk,
                         const int* __restrict__ ids,
                         float* __restrict__ out,
                         float* __restrict__ partial,
                         unsigned int* __restrict__ counter) {
    const int c  = threadIdx.x;        // channel 0..63
    const int bs = blockIdx.x;         // 0..B*NUM_SAMPLES-1
    const int b  = bs >> 8;            // / NUM_SAMPLES
    const int s  = bs & (NUM_SAMPLES - 1);

    const int hi = ids[2 * s + 0];
    const int wi = ids[2 * s + 1];

    const size_t HW   = (size_t)IMG_H * IMG_W;
    const size_t base = ((size_t)(b * CH + c)) * HW + (size_t)hi * IMG_W + wi;

    // load 3x3 patch for both tensors (18 independent loads, issued together)
    float qv[9], kv[9];
#pragma unroll
    for (int r = 0; r < 3; ++r) {
#pragma unroll
        for (int col = 0; col < 3; ++col) {
            qv[r * 3 + col] = fq[base + (size_t)r * IMG_W + col];
            kv[r * 3 + col] = fk[base + (size_t)r * IMG_W + col];
        }
    }

    const float qc = qv[4];   // center (hi+1, wi+1)
    const float kc = kv[4];

    // neighbor flat indices in the 3x3 patch (skip center 4)
    const int nidx[8] = {0, 1, 2, 3, 5, 6, 7, 8};

    float dq[8], dk[8];
#pragma unroll
    for (int n = 0; n < 8; ++n) {
        dq[n] = qv[nidx[n]] - qc;
        dk[n] = kv[nidx[n]] - kc;
    }

    float acc = 0.0f;
#pragma unroll
    for (int n = 0; n < 8; ++n) {
        const float sq  = wave_reduce_sum(dq[n] * dq[n]);
        const float sk  = wave_reduce_sum(dk[n] * dk[n]);
        const float rnq = 1.0f / (sqrtf(sq) + 1e-7f);
        const float rnk = 1.0f / (sqrtf(sk) + 1e-7f);
        acc += fabsf(dq[n] * rnq - dk[n] * rnk);
    }

    acc = wave_reduce_sum(acc);
    if (c == 0) partial[bs] = acc;

    // ---- deterministic single-kernel finalization (threadfence reduction) ----
    __threadfence();                     // make partial[bs] device-visible
    __shared__ unsigned int rank;
    if (c == 0) rank = atomicAdd(counter, 1u);   // device-scope
    __syncthreads();
    if (rank == NBLOCKS - 1) {
        __threadfence();                 // acquire: see all partials
        float v = 0.0f;
#pragma unroll
        for (int i = 0; i < NBLOCKS / 64; ++i)   // 32 per lane, fixed order
            v += partial[i * 64 + c];
        v = wave_reduce_sum(v);
        if (c == 0) {
            // mean over B * C * NUM_SAMPLES * 8 = 1048576 elements
            out[0] = v * (1.0f / 1048576.0f);
        }
    }
}

extern "C" void kernel_launch(void* const* d_in, const int* in_sizes, int n_in,
                              void* d_out, int out_size, void* d_ws, size_t ws_size,
                              hipStream_t stream) {
    const float* fq  = (const float*)d_in[0];
    const float* fk  = (const float*)d_in[1];
    const int*   ids = (const int*)d_in[2];
    float* out     = (float*)d_out;
    float* partial = (float*)d_ws;                       // 2048 * 4 = 8 KB
    unsigned int* counter = (unsigned int*)((char*)d_ws + 8192);

    // zero the arrival counter every call (graph-safe, deterministic replays)
    hipMemsetAsync(counter, 0, sizeof(unsigned int), stream);

    fused_sample_diff_kernel<<<NBLOCKS, 64, 0, stream>>>(fq, fk, ids, out,
                                                         partial, counter);
}

// Round 3
// 29.677 us; speedup vs baseline: 4.1177x; 4.1177x over previous
//
#include <hip/hip_runtime.h>
#include <hip/hip_bf16.h>

#define NUM_SAMPLES 256
#define CH 64
#define IMG_H 512
#define IMG_W 512
#define BATCH 8
#define NBLOCKS (BATCH * NUM_SAMPLES)   // 2048

__device__ __forceinline__ float wave_reduce_sum(float v) {
    // full-wave (64-lane) butterfly; all lanes end with the total
    v += __shfl_xor(v, 32, 64);
    v += __shfl_xor(v, 16, 64);
    v += __shfl_xor(v, 8, 64);
    v += __shfl_xor(v, 4, 64);
    v += __shfl_xor(v, 2, 64);
    v += __shfl_xor(v, 1, 64);
    return v;
}

// One block of 2 waves per (b, s): wave 0 -> feat_q, wave 1 -> feat_k.
// Lane = channel. k-wave passes its normalized vectors to q-wave via LDS.
__global__ void __launch_bounds__(128)
sample_diff_kernel(const float* __restrict__ fq,
                   const float* __restrict__ fk,
                   const int* __restrict__ ids,
                   float* __restrict__ partial) {
    const int c   = threadIdx.x & 63;   // channel 0..63
    const int wid = threadIdx.x >> 6;   // 0 = q, 1 = k
    const int bs  = blockIdx.x;         // 0..B*NUM_SAMPLES-1
    const int b   = bs >> 8;            // / NUM_SAMPLES
    const int s   = bs & (NUM_SAMPLES - 1);

    const int hi = ids[2 * s + 0];
    const int wi = ids[2 * s + 1];

    const float* __restrict__ src = (wid == 0) ? fq : fk;

    const size_t HW   = (size_t)IMG_H * IMG_W;
    const size_t base = ((size_t)(b * CH + c)) * HW + (size_t)hi * IMG_W + wi;

    // load this tensor's 3x3 patch (9 independent loads)
    float pv[9];
#pragma unroll
    for (int r = 0; r < 3; ++r) {
#pragma unroll
        for (int col = 0; col < 3; ++col) {
            pv[r * 3 + col] = src[base + (size_t)r * IMG_W + col];
        }
    }

    const float ctr = pv[4];   // center (hi+1, wi+1)

    float d[8];
    d[0] = pv[0] - ctr; d[1] = pv[1] - ctr; d[2] = pv[2] - ctr;
    d[3] = pv[3] - ctr; d[4] = pv[5] - ctr; d[5] = pv[6] - ctr;
    d[6] = pv[7] - ctr; d[7] = pv[8] - ctr;

    // per-neighbor L2 normalization over the 64 channels (this wave)
    float nv[8];
#pragma unroll
    for (int n = 0; n < 8; ++n) {
        const float ss = wave_reduce_sum(d[n] * d[n]);
        nv[n] = d[n] * (1.0f / (sqrtf(ss) + 1e-7f));
    }

    // k-wave publishes its normalized vectors; q-wave computes the diff
    __shared__ float kx[8][64];         // stride-1 in lane -> conflict-free
    if (wid == 1) {
#pragma unroll
        for (int n = 0; n < 8; ++n) kx[n][c] = nv[n];
    }
    __syncthreads();
    if (wid == 0) {
        float acc = 0.0f;
#pragma unroll
        for (int n = 0; n < 8; ++n) acc += fabsf(nv[n] - kx[n][c]);
        acc = wave_reduce_sum(acc);
        if (c == 0) partial[bs] = acc;
    }
}

__global__ void __launch_bounds__(64)
final_reduce_kernel(const float* __restrict__ partial, float* __restrict__ out) {
    const int c = threadIdx.x;
    float v = 0.0f;
#pragma unroll
    for (int i = 0; i < NBLOCKS / 64; ++i)   // 32 per lane, fixed order
        v += partial[i * 64 + c];
    v = wave_reduce_sum(v);
    if (c == 0) {
        // mean over B * C * NUM_SAMPLES * 8 = 1048576 elements
        out[0] = v * (1.0f / 1048576.0f);
    }
}

extern "C" void kernel_launch(void* const* d_in, const int* in_sizes, int n_in,
                              void* d_out, int out_size, void* d_ws, size_t ws_size,
                              hipStream_t stream) {
    const float* fq  = (const float*)d_in[0];
    const float* fk  = (const float*)d_in[1];
    const int*   ids = (const int*)d_in[2];
    float* out     = (float*)d_out;
    float* partial = (float*)d_ws;   // 2048 * 4 = 8 KB

    sample_diff_kernel<<<NBLOCKS, 128, 0, stream>>>(fq, fk, ids, partial);
    final_reduce_kernel<<<1, 64, 0, stream>>>(partial, out);
}

// Round 4
// 28.365 us; speedup vs baseline: 4.3083x; 1.0463x over previous
//
#include <hip/hip_runtime.h>
#include <hip/hip_bf16.h>

#define NUM_SAMPLES 256
#define CH 64
#define IMG_H 512
#define IMG_W 512
#define BATCH 8
#define NBLOCKS (BATCH * NUM_SAMPLES)   // 2048

__device__ __forceinline__ float wave_reduce_sum(float v) {
    // full-wave (64-lane) butterfly; all lanes end with the total
    v += __shfl_xor(v, 32, 64);
    v += __shfl_xor(v, 16, 64);
    v += __shfl_xor(v, 8, 64);
    v += __shfl_xor(v, 4, 64);
    v += __shfl_xor(v, 2, 64);
    v += __shfl_xor(v, 1, 64);
    return v;
}

// One block of 4 waves per (b, s): wave = (tensor, half-of-neighbors).
//   wid 0: q, neighbors 0-3    wid 1: k, neighbors 0-3
//   wid 2: q, neighbors 4-7    wid 3: k, neighbors 4-7
// Lane = channel. Each wave: 5 loads (center + 4 neighbors), 4 norm-reduces.
// k-waves publish normalized vectors via LDS; q-waves take |q̂ - k̂|.
__global__ void __launch_bounds__(256)
sample_diff_kernel(const float* __restrict__ fq,
                   const float* __restrict__ fk,
                   const int* __restrict__ ids,
                   float* __restrict__ partial) {
    const int c    = threadIdx.x & 63;   // channel 0..63
    const int wid  = threadIdx.x >> 6;   // 0..3
    const int tk   = wid & 1;            // 0 = q, 1 = k
    const int half = wid >> 1;           // 0 = neighbors 0-3, 1 = neighbors 4-7
    const int bs   = blockIdx.x;
    const int b    = bs >> 8;
    const int s    = bs & (NUM_SAMPLES - 1);

    const int hi = ids[2 * s + 0];
    const int wi = ids[2 * s + 1];

    const float* __restrict__ src = tk ? fk : fq;

    const size_t HW   = (size_t)IMG_H * IMG_W;
    const size_t base = ((size_t)(b * CH + c)) * HW + (size_t)hi * IMG_W + wi;

    // 5 independent loads: center + this half's 4 neighbors
    float ctr, nb[4];
    ctr = src[base + IMG_W + 1];
    if (half == 0) {
        nb[0] = src[base + 0];              // (0,0)
        nb[1] = src[base + 1];              // (0,1)
        nb[2] = src[base + 2];              // (0,2)
        nb[3] = src[base + IMG_W];          // (1,0)
    } else {
        nb[0] = src[base + IMG_W + 2];      // (1,2)
        nb[1] = src[base + 2 * IMG_W];      // (2,0)
        nb[2] = src[base + 2 * IMG_W + 1];  // (2,1)
        nb[3] = src[base + 2 * IMG_W + 2];  // (2,2)
    }

    // per-neighbor diff + L2 normalization over the 64 channels
    float nv[4];
#pragma unroll
    for (int n = 0; n < 4; ++n) {
        const float d  = nb[n] - ctr;
        const float ss = wave_reduce_sum(d * d);
        nv[n] = d * (1.0f / (sqrtf(ss) + 1e-7f));
    }

    // k-waves publish normalized vectors; q-waves compute |q̂ - k̂|
    __shared__ float kx[2][4][64];       // [half][neighbor][lane] — conflict-free
    __shared__ float sm[2];
    if (tk == 1) {
#pragma unroll
        for (int n = 0; n < 4; ++n) kx[half][n][c] = nv[n];
    }
    __syncthreads();
    if (tk == 0) {
        float acc = 0.0f;
#pragma unroll
        for (int n = 0; n < 4; ++n) acc += fabsf(nv[n] - kx[half][n][c]);
        acc = wave_reduce_sum(acc);
        if (c == 0) sm[half] = acc;
    }
    __syncthreads();
    if (threadIdx.x == 0) partial[bs] = sm[0] + sm[1];
}

__global__ void __launch_bounds__(64)
final_reduce_kernel(const float* __restrict__ partial, float* __restrict__ out) {
    const int c = threadIdx.x;
    float v = 0.0f;
#pragma unroll
    for (int i = 0; i < NBLOCKS / 64; ++i)   // 32 per lane, fixed order
        v += partial[i * 64 + c];
    v = wave_reduce_sum(v);
    if (c == 0) {
        // mean over B * C * NUM_SAMPLES * 8 = 1048576 elements
        out[0] = v * (1.0f / 1048576.0f);
    }
}

extern "C" void kernel_launch(void* const* d_in, const int* in_sizes, int n_in,
                              void* d_out, int out_size, void* d_ws, size_t ws_size,
                              hipStream_t stream) {
    const float* fq  = (const float*)d_in[0];
    const float* fk  = (const float*)d_in[1];
    const int*   ids = (const int*)d_in[2];
    float* out     = (float*)d_out;
    float* partial = (float*)d_ws;   // 2048 * 4 = 8 KB

    sample_diff_kernel<<<NBLOCKS, 256, 0, stream>>>(fq, fk, ids, partial);
    final_reduce_kernel<<<1, 64, 0, stream>>>(partial, out);
}